// Round 1
// 366.675 us; speedup vs baseline: 1.0075x; 1.0075x over previous
//
#include <hip/hip_runtime.h>

// Segment-average pooling, sort + single-phase ping-pong LDS scatter/reduce.
//   input  [B=8, C=128, N=65536] fp32, labels [B, N] int32 in [0, 1024)
//   out    [B, S=1024, C=128] fp32 segment means
//
// R10: depth-2 register prefetch + reduce-first phase order.
// R9's loop issued tile k+1's loads AFTER the vmcnt drain for tile k, giving
// only (reduce+barrier) of issue->consume slack -- below loaded-HBM latency,
// and the barrier phase-locks all 16 waves so the block stalls collectively.
// Now: two named register sets (A/B, static indexing), manually 2x-unrolled
// loop, per phase: reduce(k-1) -> scatter(k) [waits vmcnt(4); the newer set
// stays in flight] -> issue(k+2) -> lds_barrier. Slack = ~2 full phases.
// Issues are unconditional with clamped tile index so the compiler keeps
// counted vmcnt (a branchy issue would force vmcnt(0) every phase).

#define BB 8
#define CC 128
#define NPIX 65536      // 256*256
#define SS 1024
#define TILE 2048
#define NTILES (NPIX / TILE)   // 32
#define THREADS 1024

#define POS_ELEMS (BB * NPIX)           // u16 sorted position within tile
#define OFF_ELEMS (BB * NTILES * SS)    // u16 exclusive offsets per tile

// size-preserving XOR swizzle: e=8q+r -> 8q + (r ^ (q&7)); bijective,
// spreads reduce-run banks, costs 1 VALU op, no LDS padding.
__device__ __forceinline__ int swz(int e) { return e ^ ((e >> 3) & 7); }

// LDS-only barrier: orders LDS across waves WITHOUT draining vmcnt, so
// prefetched global loads stay in flight across it.
__device__ __forceinline__ void lds_barrier() {
  asm volatile("s_waitcnt lgkmcnt(0)\n\ts_barrier" ::: "memory");
}

// ---------------- Kernel A: per-tile counting sort metadata ----------------
__global__ __launch_bounds__(THREADS, 1) void sort_kernel(
    const int* __restrict__ seg, unsigned short* __restrict__ pos,
    unsigned short* __restrict__ tileoff) {
  __shared__ unsigned int hist[SS];
  __shared__ unsigned int wsum[16];
  const int b   = blockIdx.x / NTILES;
  const int t   = blockIdx.x % NTILES;
  const int tid = threadIdx.x;

  hist[tid] = 0u;   // THREADS == SS
  __syncthreads();

  const int base = b * NPIX + t * TILE;
  const int2 lab = reinterpret_cast<const int2*>(seg + base)[tid];
  const unsigned int r0 = atomicAdd(&hist[lab.x], 1u);
  const unsigned int r1 = atomicAdd(&hist[lab.y], 1u);
  __syncthreads();

  const unsigned int cnt = hist[tid];
  // inclusive wave-scan (64 lanes, shuffle, no barriers)
  unsigned int v = cnt;
  #pragma unroll
  for (int off = 1; off < 64; off <<= 1) {
    const unsigned int u = __shfl_up(v, off);
    if ((tid & 63) >= off) v += u;
  }
  const int w = tid >> 6;
  if ((tid & 63) == 63) wsum[w] = v;
  __syncthreads();
  if (tid < 16) {   // scan the 16 wave totals
    unsigned int x = wsum[tid];
    #pragma unroll
    for (int off = 1; off < 16; off <<= 1) {
      const unsigned int u = __shfl_up(x, off);
      if (tid >= off) x += u;
    }
    wsum[tid] = x;
  }
  __syncthreads();
  const unsigned int woff = (w == 0) ? 0u : wsum[w - 1];
  const unsigned int excl = woff + v - cnt;   // exclusive offset of segment tid
  tileoff[(b * NTILES + t) * SS + tid] = (unsigned short)excl;
  hist[tid] = excl;
  __syncthreads();

  ushort2 p2;
  p2.x = (unsigned short)(hist[lab.x] + r0);
  p2.y = (unsigned short)(hist[lab.y] + r1);
  reinterpret_cast<ushort2*>(pos + base)[tid] = p2;
}

// ---------------- Kernel B: depth-2 ping-pong scatter/reduce ---------------
// 512 blocks = (image b, channel pair c0); 2 blocks/CU; thread == segment.
__global__ __launch_bounds__(THREADS, 8) void aggr_kernel(
    const float* __restrict__ inp, const unsigned short* __restrict__ pos,
    const unsigned short* __restrict__ tileoff, float* __restrict__ out) {
  __shared__ float2 buf[2][TILE];               // 2 x 16 KiB ping-pong
  __shared__ unsigned short offl[2][SS + 1];    // ping-pong offsets

  const int b   = blockIdx.x >> 6;          // / (CC/2)
  const int c0  = (blockIdx.x & 63) << 1;   // channel pair base
  const int s   = threadIdx.x;              // segment id
  const int tphase = (blockIdx.x & 1) ? (NTILES / 2) : 0;  // desync pair

  const float* __restrict__ pl0 = inp + ((size_t)b * CC + c0) * NPIX;
  const float* __restrict__ pl1 = pl0 + NPIX;
  const unsigned short* __restrict__ pbase = pos + b * NPIX;
  const unsigned short* __restrict__ tob = tileoff + b * NTILES * SS;

  float a0 = 0.f, a1 = 0.f;
  int cnt = 0;

// clamped tile index: keeps over-issued prefetches in-bounds without a branch
#define TIDX(k) ((((k) < NTILES ? (k) : (NTILES - 1)) + tphase) & (NTILES - 1))

#define ISSUE(V0, V1, P, O, k) do { const int tn_ = TIDX(k); \
    V0 = reinterpret_cast<const float2*>(pl0 + tn_ * TILE)[s]; \
    V1 = reinterpret_cast<const float2*>(pl1 + tn_ * TILE)[s]; \
    P  = reinterpret_cast<const ushort2*>(pbase + tn_ * TILE)[s]; \
    O  = tob[tn_ * SS + s]; } while (0)

#define SCATTER(cur, V0, V1, P, O) do { \
    if (s == 0) offl[cur][SS] = (unsigned short)TILE; \
    offl[cur][s] = O; \
    buf[cur][swz(P.x)] = make_float2(V0.x, V1.x); \
    buf[cur][swz(P.y)] = make_float2(V0.y, V1.y); } while (0)

#define REDUCE(prv) do { \
    const int beg_ = offl[prv][s]; \
    const int end_ = offl[prv][s + 1]; \
    cnt += end_ - beg_; \
    int j_ = beg_; \
    for (; j_ + 2 <= end_; j_ += 2) { \
      const float2 u_ = buf[prv][swz(j_)]; \
      const float2 w_ = buf[prv][swz(j_ + 1)]; \
      a0 += u_.x + w_.x; a1 += u_.y + w_.y; } \
    if (j_ < end_) { \
      const float2 u_ = buf[prv][swz(j_)]; \
      a0 += u_.x; a1 += u_.y; } } while (0)

  // two named register sets -> all indexing compile-time static (no scratch)
  float2 Av0, Av1, Bv0, Bv1;
  ushort2 Ap, Bp;
  unsigned short Ao, Bo;

  ISSUE(Av0, Av1, Ap, Ao, 0);
  ISSUE(Bv0, Bv1, Bp, Bo, 1);

  // tile 0 (even, A -> buf0): no reduce yet; refill A with tile 2
  SCATTER(0, Av0, Av1, Ap, Ao);
  ISSUE(Av0, Av1, Ap, Ao, 2);
  lds_barrier();

  for (int k = 1; k + 1 < NTILES; k += 2) {
    // odd tile k: reduce tile k-1 (buf0); scatter B -> buf1; refill B (k+2)
    REDUCE(0);
    SCATTER(1, Bv0, Bv1, Bp, Bo);
    ISSUE(Bv0, Bv1, Bp, Bo, k + 2);
    lds_barrier();
    // even tile k+1: reduce tile k (buf1); scatter A -> buf0; refill A (k+3)
    REDUCE(1);
    SCATTER(0, Av0, Av1, Ap, Ao);
    ISSUE(Av0, Av1, Ap, Ao, k + 3);
    lds_barrier();
  }

  // last tile (NTILES-1, odd): reduce tile NTILES-2 (buf0); scatter B -> buf1
  REDUCE(0);
  SCATTER(1, Bv0, Bv1, Bp, Bo);
  lds_barrier();
  // epilogue: reduce the final scattered tile
  REDUCE(1);

#undef TIDX
#undef ISSUE
#undef SCATTER
#undef REDUCE

  const float inv = 1.0f / (float)max(cnt, 1);
  reinterpret_cast<float2*>(out + ((size_t)(b * SS + s)) * CC + c0)[0] =
      make_float2(a0 * inv, a1 * inv);
}

// ---------------- Fallback (R2): LDS-atomic version, needs no ws -----------
__global__ __launch_bounds__(THREADS, 1) void seg_avg_kernel(
    const float* __restrict__ inp, const int* __restrict__ seg,
    float* __restrict__ out) {
  __shared__ float acc[SS * 5];
  const int b   = blockIdx.x >> 5;
  const int c0  = (blockIdx.x & 31) << 2;
  const int tid = threadIdx.x;
  for (int i = tid; i < SS * 5; i += THREADS) acc[i] = 0.0f;
  __syncthreads();
  const float4* __restrict__ p0 =
      reinterpret_cast<const float4*>(inp + ((size_t)b * CC + c0) * NPIX);
  const int4* __restrict__ lab = reinterpret_cast<const int4*>(seg + (size_t)b * NPIX);
  const int Q = NPIX / 4;
  int* iacc = reinterpret_cast<int*>(acc);
  for (int i = 0; i < NPIX / (4 * THREADS); ++i) {
    const int p = i * THREADS + tid;
    const int4 s4 = lab[p];
    const float4 v0 = p0[p], v1 = p0[p + Q], v2 = p0[p + 2 * Q], v3 = p0[p + 3 * Q];
    const int a0 = s4.x * 5, a1 = s4.y * 5, a2 = s4.z * 5, a3 = s4.w * 5;
    unsafeAtomicAdd(&acc[a0 + 0], v0.x); unsafeAtomicAdd(&acc[a0 + 1], v1.x);
    unsafeAtomicAdd(&acc[a0 + 2], v2.x); unsafeAtomicAdd(&acc[a0 + 3], v3.x);
    atomicAdd(&iacc[a0 + 4], 1);
    unsafeAtomicAdd(&acc[a1 + 0], v0.y); unsafeAtomicAdd(&acc[a1 + 1], v1.y);
    unsafeAtomicAdd(&acc[a1 + 2], v2.y); unsafeAtomicAdd(&acc[a1 + 3], v3.y);
    atomicAdd(&iacc[a1 + 4], 1);
    unsafeAtomicAdd(&acc[a2 + 0], v0.z); unsafeAtomicAdd(&acc[a2 + 1], v1.z);
    unsafeAtomicAdd(&acc[a2 + 2], v2.z); unsafeAtomicAdd(&acc[a2 + 3], v3.z);
    atomicAdd(&iacc[a2 + 4], 1);
    unsafeAtomicAdd(&acc[a3 + 0], v0.w); unsafeAtomicAdd(&acc[a3 + 1], v1.w);
    unsafeAtomicAdd(&acc[a3 + 2], v2.w); unsafeAtomicAdd(&acc[a3 + 3], v3.w);
    atomicAdd(&iacc[a3 + 4], 1);
  }
  __syncthreads();
  for (int i = tid; i < SS * 4; i += THREADS) {
    const int s = i >> 2, c = i & 3;
    const float cntf = (float)iacc[s * 5 + 4];
    out[((size_t)(b * SS + s)) * CC + c0 + c] = acc[s * 5 + c] / fmaxf(cntf, 1.0f);
  }
}

extern "C" void kernel_launch(void* const* d_in, const int* in_sizes, int n_in,
                              void* d_out, int out_size, void* d_ws, size_t ws_size,
                              hipStream_t stream) {
  const float* inp = (const float*)d_in[0];
  const int*   seg = (const int*)d_in[1];
  float*       out = (float*)d_out;

  const size_t need = (size_t)POS_ELEMS * 2 + (size_t)OFF_ELEMS * 2;  // 1.5 MiB
  if (ws_size >= need) {
    unsigned short* pos  = (unsigned short*)d_ws;
    unsigned short* toff = pos + POS_ELEMS;
    sort_kernel<<<BB * NTILES, THREADS, 0, stream>>>(seg, pos, toff);
    aggr_kernel<<<BB * (CC / 2), THREADS, 0, stream>>>(inp, pos, toff, out);
  } else {
    seg_avg_kernel<<<BB * (CC / 4), THREADS, 0, stream>>>(inp, seg, out);
  }
}